// Round 7
// baseline (282.186 us; speedup 1.0000x reference)
//
#include <hip/hip_runtime.h>
#include <cstdint>

#define BATCH 4
#define CPD 64
#define RES 64
#define NS 131072
#define NF 512
#define FS 2048
#define HID 16

typedef _Float16 __attribute__((ext_vector_type(8))) f16x8;
typedef float __attribute__((ext_vector_type(16))) f32x16;

typedef union { uint4 u; f16x8 v; } Frag;

// ---------------------------------------------------------------------------
// K1: damping + sequential scan (unchanged; tiny cost, passed)
// ---------------------------------------------------------------------------
__global__ __launch_bounds__(256) void k_scan(const float* __restrict__ forces,
                                              const float* __restrict__ dmod,
                                              const float* __restrict__ dparam,
                                              float* __restrict__ damped_t) {
  __shared__ float f_lds[64][129];
  __shared__ float d_lds[64][129];
  const int b = blockIdx.x;
  const int tid = threadIdx.x;
  float dbase = 0.f, carry = 0.f;
  if (tid < 64) {
    float dp = dparam[tid];
    dbase = 0.5f + (0.9999f - 0.5f) / (1.f + expf(-dp));
  }
  for (int ch = 0; ch < 4; ++ch) {
    const int t0 = ch * 128;
    __syncthreads();
    for (int idx = tid; idx < 64 * 128; idx += 256) {
      int c = idx >> 7, tl = idx & 127;
      f_lds[c][tl] = forces[(b * CPD + c) * NF + t0 + tl];
      d_lds[c][tl] = dmod[(b * CPD + c) * NF + t0 + tl];
    }
    __syncthreads();
    if (tid < 64) {
      const int c = tid;
      for (int tl = 0; tl < 128; ++tl) {
        float d = dbase - fabsf(d_lds[c][tl]);
        d = fminf(fmaxf(d, 0.f), 1.f);
        float f = f_lds[c][tl];
        float out = (ch == 0 && tl == 0) ? f : (f + carry) * d;
        carry = out;
        damped_t[(b * NF + t0 + tl) * CPD + c] = out;
      }
    }
  }
}

// ---------------------------------------------------------------------------
// K2: hypernetwork + routing einsum + to_ctrl (unchanged)
// ---------------------------------------------------------------------------
__global__ __launch_bounds__(256) void k_hyper(const float* __restrict__ damped_t,
                                               const float* __restrict__ routing,
                                               const float* __restrict__ W1,
                                               const float* __restrict__ b1,
                                               const float* __restrict__ W2,
                                               const float* __restrict__ b2,
                                               const float* __restrict__ to_control,
                                               float* __restrict__ routed,
                                               float* __restrict__ to_ctrl) {
  __shared__ float xs[4][64];
  __shared__ float hs[4][16];
  __shared__ float rs[4][64];
  const int blk = blockIdx.x;
  const int b = blk >> 7;
  const int t0 = (blk & 127) * 4;
  const int lt = threadIdx.x >> 6;
  const int d = threadIdx.x & 63;
  const int t = t0 + lt;

  xs[lt][d] = damped_t[(b * NF + t) * CPD + d];
  __syncthreads();
  if (d < HID) {
    float a = b1[d];
    for (int c = 0; c < CPD; ++c) a = fmaf(xs[lt][c], W1[c * HID + d], a);
    hs[lt][d] = a > 0.f ? a : 0.2f * a;
  }
  __syncthreads();
  float hreg[HID];
#pragma unroll
  for (int j = 0; j < HID; ++j) hreg[j] = hs[lt][j];

  float acc = 0.f;
  for (int c = 0; c < CPD; ++c) {
    float w = routing[c * RES + d] + b2[c * RES + d];
    const float* w2p = W2 + c * RES + d;
#pragma unroll
    for (int j = 0; j < HID; ++j) w = fmaf(hreg[j], w2p[j * (CPD * RES)], w);
    acc = fmaf(xs[lt][c], w, acc);
  }
  routed[(b * RES + d) * NF + t] = acc;
  rs[lt][d] = acc;
  __syncthreads();
  float tc = 0.f;
  for (int q = 0; q < RES; ++q) tc = fmaf(rs[lt][q], to_control[q * CPD + d], tc);
  to_ctrl[(b * CPD + d) * NF + t] = tc;
}

// ---------------------------------------------------------------------------
// K-zero: zero the atomic boundary strips (re-run every launch -> replay safe)
// ---------------------------------------------------------------------------
__global__ __launch_bounds__(256) void k_zero(float* __restrict__ reso) {
  const int chan = blockIdx.x;
  const size_t base = (size_t)chan * NS;
  for (int i = threadIdx.x; i < 4096; i += 256) {
    int y;
    if (i < 32) y = i;
    else if (i < 32 + 3072) {
      int s = 1 + ((i - 32) >> 10);
      y = 32768 * s - 992 + ((i - 32) & 1023);
    } else {
      y = 130080 + (i - 3104);
    }
    reso[base + y] = 0.f;
  }
}

// ---------------------------------------------------------------------------
// K3: block-Hankel GEMM conv, 2-phase A-sharing, round-7:
//  - filter in 8 element-shift copies (copy c = f shifted by c taps,
//    stride 267 granules): every B fragment = one aligned ds_read_b128,
//    bank-quads perfectly balanced (8 lanes/quad, 3c mod 8 bijection).
//  - manual 2-deep software pipeline (ping/pong fragments, prefetch next
//    superstep's 4 A + 2 B reads before current 8 MFMAs).
// Tap t for B (col=row, khalf h, superstep SG, phase j):
//   t = row + 8h + 16*SG + 1024j - 32;  copy c = row&7;
//   granule(c-local) = (row>>3) + h + 2*SG + 128j,  fcp_c[x] = f[x + c - 32]
// ---------------------------------------------------------------------------
#define ER_GRAN 4360        // 16B granules allocated (incl. swizzle slack)
#define ER_N 34816          // staged samples: x = 0..34815, er[x]=e[E0-x]*1024
#define FC_COPIES 8
#define FC_STRIDE 267       // granules per copy (max index 266 incl prefetch)
#define SMEM_BYTES (ER_GRAN * 16 + FC_COPIES * FC_STRIDE * 16)

__global__ __launch_bounds__(512, 2) void k_conv(const float* __restrict__ routed,
                                                 const float* __restrict__ noise,
                                                 const float* __restrict__ filters,
                                                 float* __restrict__ outp) {
  __shared__ __align__(16) unsigned char smem[SMEM_BYTES];
  unsigned char* erb = smem;
  unsigned char* fcb = smem + ER_GRAN * 16;

  const int tid = threadIdx.x;
  const int seg = blockIdx.x & 3;
  const int r = (blockIdx.x >> 2) & 63;
  const int b = blockIdx.x >> 8;
  const int SegB = seg * 32768;
  const int E0 = SegB + 32800;        // er[x] = e[E0-x]*1024
  const int chan = b * RES + r;
  const float* rp = routed + chan * NF;
  const float* npz = noise + (size_t)chan * NS;

  // ---- filter staging: 8 shift copies; copy c dword d = taps (2d+c-32, +1) ----
  {
    unsigned* f32p = (unsigned*)fcb;
    const float* fr = filters + r * FS;
    for (int c = 0; c < FC_COPIES; ++c) {
      for (int d = tid; d < FC_STRIDE * 4; d += 512) {
        int t0 = 2 * d + c - 32;
        float f0 = (t0 >= 0 && t0 < FS) ? fr[t0] : 0.f;
        float f1 = (t0 + 1 >= 0 && t0 + 1 < FS) ? fr[t0 + 1] : 0.f;
        union { _Float16 h[2]; unsigned u; } P;
        P.h[0] = (_Float16)f0;
        P.h[1] = (_Float16)f1;
        f32p[c * (FC_STRIDE * 4) + d] = P.u;
      }
    }
  }

  // ---- energy staging: pairs, f16*1024, XOR-swizzled granule layout ----
  {
    unsigned* er32 = (unsigned*)erb;
    for (int x2 = tid; x2 < ER_N / 2; x2 += 512) {
      int x = 2 * x2;
      union { _Float16 h[2]; unsigned u; } P;
#pragma unroll
      for (int k = 0; k < 2; ++k) {
        int n = E0 - x - k;
        float e = 0.f;
        if (n >= 0 && n < NS) {
          float pos = ((float)n + 0.5f) * (1.f / 256.f) - 0.5f;
          pos = fminf(fmaxf(pos, 0.f), 511.f);
          float fi = floorf(pos);
          int i0 = (int)fi;
          int i1 = min(i0 + 1, 511);
          float fr = pos - fi;
          float u = rp[i0] * (1.f - fr) + rp[i1] * fr;
          e = u * npz[n];
        }
        P.h[k] = (_Float16)(e * 1024.f);
      }
      int g = x >> 3;
      int sig = g ^ ((g >> 3) & 7);
      er32[sig * 4 + ((x & 7) >> 1)] = P.u;
    }
  }
  __syncthreads();

  const int w = tid >> 6;
  const int l = tid & 63;
  const int row = l & 31;   // A-row m == B-col n lane index
  const int h = l >> 5;     // k-half

  // A granule bases (SG=0): g = 4096 - 512w - 128*tau + 4row + h
  const int ga0 = 4096 - 512 * w + 4 * row + h;
  const int ga1 = ga0 - 128;
  const int ga2 = ga0 - 256;
  const int ga3 = ga0 - 384;
  // B granule base (SG=0, j=0): (row&7)*FC_STRIDE + (row>>3) + h
  const int qcb = (row & 7) * FC_STRIDE + (row >> 3) + h;

  f32x16 a00, a01, a02, a03, a10, a11, a12, a13;
#pragma unroll
  for (int i = 0; i < 16; ++i) {
    a00[i] = 0.f; a01[i] = 0.f; a02[i] = 0.f; a03[i] = 0.f;
    a10[i] = 0.f; a11[i] = 0.f; a12[i] = 0.f; a13[i] = 0.f;
  }

#define LOADA(DST, GB, SG_)                                                   \
  { int g = (GB) + 2 * (SG_); int ab = (g ^ ((g >> 3) & 7)) << 4;             \
    DST.u = *(const uint4*)(erb + ab); }
#define LOADBF(DST, SG_, J_)                                                  \
  { int gb = qcb + 2 * (SG_) + 128 * (J_);                                    \
    DST.u = *(const uint4*)(fcb + (gb << 4)); }
#define MFMA8(A0_, A1_, A2_, A3_, B0_, B1_)                                   \
  a00 = __builtin_amdgcn_mfma_f32_32x32x16_f16(A0_.v, B0_.v, a00, 0, 0, 0);   \
  a10 = __builtin_amdgcn_mfma_f32_32x32x16_f16(A0_.v, B1_.v, a10, 0, 0, 0);   \
  a01 = __builtin_amdgcn_mfma_f32_32x32x16_f16(A1_.v, B0_.v, a01, 0, 0, 0);   \
  a11 = __builtin_amdgcn_mfma_f32_32x32x16_f16(A1_.v, B1_.v, a11, 0, 0, 0);   \
  a02 = __builtin_amdgcn_mfma_f32_32x32x16_f16(A2_.v, B0_.v, a02, 0, 0, 0);   \
  a12 = __builtin_amdgcn_mfma_f32_32x32x16_f16(A2_.v, B1_.v, a12, 0, 0, 0);   \
  a03 = __builtin_amdgcn_mfma_f32_32x32x16_f16(A3_.v, B0_.v, a03, 0, 0, 0);   \
  a13 = __builtin_amdgcn_mfma_f32_32x32x16_f16(A3_.v, B1_.v, a13, 0, 0, 0);

  // ---- prologue: SG = 0,1, phase 0 only ----
  for (int sg = 0; sg < 2; ++sg) {
    Frag Bf, A0, A1, A2, A3;
    LOADBF(Bf, sg, 0)
    LOADA(A0, ga0, sg) LOADA(A1, ga1, sg) LOADA(A2, ga2, sg) LOADA(A3, ga3, sg)
    a00 = __builtin_amdgcn_mfma_f32_32x32x16_f16(A0.v, Bf.v, a00, 0, 0, 0);
    a01 = __builtin_amdgcn_mfma_f32_32x32x16_f16(A1.v, Bf.v, a01, 0, 0, 0);
    a02 = __builtin_amdgcn_mfma_f32_32x32x16_f16(A2.v, Bf.v, a02, 0, 0, 0);
    a03 = __builtin_amdgcn_mfma_f32_32x32x16_f16(A3.v, Bf.v, a03, 0, 0, 0);
  }

  // ---- main: SG = 2..65, both phases, 2-deep pipelined (unroll x2) ----
  {
    Frag cA0, cA1, cA2, cA3, cB0, cB1;
    Frag nA0, nA1, nA2, nA3, nB0, nB1;
    LOADA(cA0, ga0, 2) LOADA(cA1, ga1, 2) LOADA(cA2, ga2, 2) LOADA(cA3, ga3, 2)
    LOADBF(cB0, 2, 0) LOADBF(cB1, 2, 1)
    for (int it = 0; it < 32; ++it) {
      const int sgA = 2 * it + 3;     // next (odd) superstep
      const int sgB = 2 * it + 4;     // superstep after (<=66, one-past safe)
      LOADA(nA0, ga0, sgA) LOADA(nA1, ga1, sgA)
      LOADA(nA2, ga2, sgA) LOADA(nA3, ga3, sgA)
      LOADBF(nB0, sgA, 0) LOADBF(nB1, sgA, 1)
      MFMA8(cA0, cA1, cA2, cA3, cB0, cB1)
      LOADA(cA0, ga0, sgB) LOADA(cA1, ga1, sgB)
      LOADA(cA2, ga2, sgB) LOADA(cA3, ga3, sgB)
      LOADBF(cB0, sgB, 0) LOADBF(cB1, sgB, 1)
      MFMA8(nA0, nA1, nA2, nA3, nB0, nB1)
    }
  }

  // ---- global-top orphan strip gets its phase-0 half here (r6 fix) ----
  if (seg == 3 && w == 7) {
    f32x16 ax;
#pragma unroll
    for (int i = 0; i < 16; ++i) ax[i] = 0.f;
    const int ge = 4 * row + h;
    for (int sg = 0; sg < 66; ++sg) {
      Frag Bx, Ax;
      LOADBF(Bx, sg, 0)
      LOADA(Ax, ge, sg)
      ax = __builtin_amdgcn_mfma_f32_32x32x16_f16(Ax.v, Bx.v, ax, 0, 0, 0);
    }
#pragma unroll
    for (int i = 0; i < 16; ++i) a13[i] += ax[i];
  }
#undef LOADA
#undef LOADBF
#undef MFMA8

  // ---- epilogue ----
  float* cbase = outp + (size_t)chan * NS;
  const float scale = 1.f / 1024.f;

#define SUMSTORE(P0, P1, U)                                                   \
  {                                                                           \
    float* po = cbase + SegB + 4096 * w + 1024 * (U);                         \
    _Pragma("unroll")                                                         \
    for (int rg = 0; rg < 16; ++rg) {                                         \
      int crow = (rg & 3) + 8 * (rg >> 2) + 4 * h;                            \
      po[row - 32 * crow] = (P0[rg] + P1[rg]) * scale;                        \
    }                                                                         \
  }
  SUMSTORE(a01, a10, 1)
  SUMSTORE(a02, a11, 2)
  SUMSTORE(a03, a12, 3)
#undef SUMSTORE

  // exchange a13 (wave w) -> partner of wave w+1's a00
  __syncthreads();                       // everyone done reading er
  float* scr = (float*)smem;             // 8 waves x 16 regs x 64 lanes
#pragma unroll
  for (int rg = 0; rg < 16; ++rg) scr[w * 1024 + rg * 64 + l] = a13[rg];
  __syncthreads();

  if (w >= 1) {
    float* po = cbase + SegB + 4096 * w;
#pragma unroll
    for (int rg = 0; rg < 16; ++rg) {
      int crow = (rg & 3) + 8 * (rg >> 2) + 4 * h;
      po[row - 32 * crow] = (a00[rg] + scr[(w - 1) * 1024 + rg * 64 + l]) * scale;
    }
  } else {
    // w == 0: partial strip [SegB-992, SegB+32) -> atomicAdd (pre-zeroed)
#pragma unroll
    for (int rg = 0; rg < 16; ++rg) {
      int crow = (rg & 3) + 8 * (rg >> 2) + 4 * h;
      int y = SegB + row - 32 * crow;
      if (y >= 0) atomicAdd(cbase + y, a00[rg] * scale);
    }
  }
  if (w == 7) {
    // partial strip [SegB+31776, SegB+32800) -> atomicAdd (pre-zeroed)
#pragma unroll
    for (int rg = 0; rg < 16; ++rg) {
      int crow = (rg & 3) + 8 * (rg >> 2) + 4 * h;
      int y = SegB + 32768 + row - 32 * crow;
      if (y < NS) atomicAdd(cbase + y, a13[rg] * scale);
    }
  }
}

// ---------------------------------------------------------------------------
extern "C" void kernel_launch(void* const* d_in, const int* in_sizes, int n_in,
                              void* d_out, int out_size, void* d_ws, size_t ws_size,
                              hipStream_t stream) {
  const float* forces     = (const float*)d_in[0];
  const float* dmod       = (const float*)d_in[1];
  const float* noise      = (const float*)d_in[2];
  const float* dparam     = (const float*)d_in[3];
  const float* routing    = (const float*)d_in[4];
  const float* W1         = (const float*)d_in[5];
  const float* b1         = (const float*)d_in[6];
  const float* W2         = (const float*)d_in[7];
  const float* b2         = (const float*)d_in[8];
  const float* filters    = (const float*)d_in[9];
  const float* to_control = (const float*)d_in[10];

  float* out = (float*)d_out;
  float* to_ctrl = out;                                  // (B,CPD,NF)
  float* reso = out + BATCH * CPD * NF;                  // (B,RES,NS)

  float* damped_t = (float*)d_ws;                        // (B,NF,CPD)
  float* routed = damped_t + BATCH * NF * CPD;           // (B,RES,NF)

  k_scan<<<BATCH, 256, 0, stream>>>(forces, dmod, dparam, damped_t);
  k_hyper<<<BATCH * NF / 4, 256, 0, stream>>>(damped_t, routing, W1, b1, W2, b2,
                                              to_control, routed, to_ctrl);
  k_zero<<<BATCH * RES, 256, 0, stream>>>(reso);
  k_conv<<<BATCH * RES * (NS / 32768), 512, 0, stream>>>(routed, noise, filters, reso);
}

// Round 8
// 249.984 us; speedup vs baseline: 1.1288x; 1.1288x over previous
//
#include <hip/hip_runtime.h>
#include <cstdint>

#define BATCH 4
#define CPD 64
#define RES 64
#define NS 131072
#define NF 512
#define FS 2048
#define HID 16

typedef _Float16 __attribute__((ext_vector_type(8))) f16x8;
typedef float __attribute__((ext_vector_type(16))) f32x16;

typedef union { uint4 u; f16x8 v; } Frag;

// ---------------------------------------------------------------------------
// K1: damping + sequential scan (unchanged; tiny cost, passed)
// ---------------------------------------------------------------------------
__global__ __launch_bounds__(256) void k_scan(const float* __restrict__ forces,
                                              const float* __restrict__ dmod,
                                              const float* __restrict__ dparam,
                                              float* __restrict__ damped_t) {
  __shared__ float f_lds[64][129];
  __shared__ float d_lds[64][129];
  const int b = blockIdx.x;
  const int tid = threadIdx.x;
  float dbase = 0.f, carry = 0.f;
  if (tid < 64) {
    float dp = dparam[tid];
    dbase = 0.5f + (0.9999f - 0.5f) / (1.f + expf(-dp));
  }
  for (int ch = 0; ch < 4; ++ch) {
    const int t0 = ch * 128;
    __syncthreads();
    for (int idx = tid; idx < 64 * 128; idx += 256) {
      int c = idx >> 7, tl = idx & 127;
      f_lds[c][tl] = forces[(b * CPD + c) * NF + t0 + tl];
      d_lds[c][tl] = dmod[(b * CPD + c) * NF + t0 + tl];
    }
    __syncthreads();
    if (tid < 64) {
      const int c = tid;
      for (int tl = 0; tl < 128; ++tl) {
        float d = dbase - fabsf(d_lds[c][tl]);
        d = fminf(fmaxf(d, 0.f), 1.f);
        float f = f_lds[c][tl];
        float out = (ch == 0 && tl == 0) ? f : (f + carry) * d;
        carry = out;
        damped_t[(b * NF + t0 + tl) * CPD + c] = out;
      }
    }
  }
}

// ---------------------------------------------------------------------------
// K2: hypernetwork + routing einsum + to_ctrl (unchanged)
// ---------------------------------------------------------------------------
__global__ __launch_bounds__(256) void k_hyper(const float* __restrict__ damped_t,
                                               const float* __restrict__ routing,
                                               const float* __restrict__ W1,
                                               const float* __restrict__ b1,
                                               const float* __restrict__ W2,
                                               const float* __restrict__ b2,
                                               const float* __restrict__ to_control,
                                               float* __restrict__ routed,
                                               float* __restrict__ to_ctrl) {
  __shared__ float xs[4][64];
  __shared__ float hs[4][16];
  __shared__ float rs[4][64];
  const int blk = blockIdx.x;
  const int b = blk >> 7;
  const int t0 = (blk & 127) * 4;
  const int lt = threadIdx.x >> 6;
  const int d = threadIdx.x & 63;
  const int t = t0 + lt;

  xs[lt][d] = damped_t[(b * NF + t) * CPD + d];
  __syncthreads();
  if (d < HID) {
    float a = b1[d];
    for (int c = 0; c < CPD; ++c) a = fmaf(xs[lt][c], W1[c * HID + d], a);
    hs[lt][d] = a > 0.f ? a : 0.2f * a;
  }
  __syncthreads();
  float hreg[HID];
#pragma unroll
  for (int j = 0; j < HID; ++j) hreg[j] = hs[lt][j];

  float acc = 0.f;
  for (int c = 0; c < CPD; ++c) {
    float w = routing[c * RES + d] + b2[c * RES + d];
    const float* w2p = W2 + c * RES + d;
#pragma unroll
    for (int j = 0; j < HID; ++j) w = fmaf(hreg[j], w2p[j * (CPD * RES)], w);
    acc = fmaf(xs[lt][c], w, acc);
  }
  routed[(b * RES + d) * NF + t] = acc;
  rs[lt][d] = acc;
  __syncthreads();
  float tc = 0.f;
  for (int q = 0; q < RES; ++q) tc = fmaf(rs[lt][q], to_control[q * CPD + d], tc);
  to_ctrl[(b * CPD + d) * NF + t] = tc;
}

// ---------------------------------------------------------------------------
// K-zero: zero the atomic boundary strips (re-run every launch -> replay safe)
// Strips per channel: [0,32); [16384s-992, 16384s+32) s=1..7; [130080,131072)
// Total 8192 elements per channel.
// ---------------------------------------------------------------------------
__global__ __launch_bounds__(256) void k_zero(float* __restrict__ reso) {
  const int chan = blockIdx.x;
  const size_t base = (size_t)chan * NS;
  for (int i = threadIdx.x; i < 8192; i += 256) {
    int y;
    if (i < 32) y = i;
    else if (i < 32 + 7168) {
      int s = 1 + ((i - 32) >> 10);
      y = 16384 * s - 992 + ((i - 32) & 1023);
    } else {
      y = 130080 + (i - 7200);
    }
    reso[base + y] = 0.f;
  }
}

// ---------------------------------------------------------------------------
// K3: block-Hankel GEMM conv, round-8: occupancy-first.
// 2 tiles x 2 phases per wave = 4 accumulators (64 AGPR) -> <=128 regs ->
// 4 waves/SIMD (forced via __launch_bounds__(512,4)), 2 blocks/CU.
// Block spans 16384 outputs (8 waves x 2 tiles x 1024); grid 2048.
// Per superstep: 2 A b128 + 2 B b128 reads -> 4 MFMAs (A shared across
// phases, B shared across tiles).
//   A_T[m][i] = e[Q_T - 32m - 16sg - i], Q_T = NB + 1024T + 32, T = 2w+tau
//   B_j[i][n] = f[n - 32 + 16sg + 1024j + i]
// Phase 0: sg in [0,66); phase 1: sg in [2,66). Pair acc(T,0)+acc(T-1,1).
// er granule for (T, sg): 2048 - 128T + 4row + h + 2sg (XOR-swizzled).
// fcp copy c=row&7, granule (row>>3) + h + 2sg + 128j, stride 267.
// ---------------------------------------------------------------------------
#define SPAN 16384
#define ER_GRAN 2312        // 16B granules incl swizzle slack (max used 2303)
#define ER_N 18432          // staged samples; er[x] = e[E0-x]*1024
#define FC_COPIES 8
#define FC_STRIDE 267       // granules per copy; 267 mod 8 = 3 (quad bijection)
#define SMEM_BYTES (ER_GRAN * 16 + FC_COPIES * FC_STRIDE * 16)  // 71168 B

__global__ __launch_bounds__(512, 4) void k_conv(const float* __restrict__ routed,
                                                 const float* __restrict__ noise,
                                                 const float* __restrict__ filters,
                                                 float* __restrict__ outp) {
  __shared__ __align__(16) unsigned char smem[SMEM_BYTES];
  unsigned char* erb = smem;
  unsigned char* fcb = smem + ER_GRAN * 16;

  const int tid = threadIdx.x;
  const int seg = blockIdx.x & 7;
  const int r = (blockIdx.x >> 3) & 63;
  const int b = blockIdx.x >> 9;
  const int NB = seg * SPAN;
  const int E0 = NB + SPAN + 32;      // er[x] = e[E0-x]*1024
  const int chan = b * RES + r;
  const float* rp = routed + chan * NF;
  const float* npz = noise + (size_t)chan * NS;

  // ---- filter staging: 8 shift copies; copy c dword d = taps (2d+c-32, +1) ----
  {
    unsigned* f32p = (unsigned*)fcb;
    const float* fr = filters + r * FS;
    for (int idx = tid; idx < FC_COPIES * FC_STRIDE * 4; idx += 512) {
      int c = idx / (FC_STRIDE * 4);
      int d = idx - c * (FC_STRIDE * 4);
      int t0 = 2 * d + c - 32;
      float f0 = (t0 >= 0 && t0 < FS) ? fr[t0] : 0.f;
      float f1 = (t0 + 1 >= 0 && t0 + 1 < FS) ? fr[t0 + 1] : 0.f;
      union { _Float16 h[2]; unsigned u; } P;
      P.h[0] = (_Float16)f0;
      P.h[1] = (_Float16)f1;
      f32p[idx] = P.u;
    }
  }

  // ---- energy staging: pairs, f16*1024, XOR-swizzled granule layout ----
  {
    unsigned* er32 = (unsigned*)erb;
    for (int x2 = tid; x2 < ER_N / 2; x2 += 512) {
      int x = 2 * x2;
      union { _Float16 h[2]; unsigned u; } P;
#pragma unroll
      for (int k = 0; k < 2; ++k) {
        int n = E0 - x - k;
        float e = 0.f;
        if (n >= 0 && n < NS) {
          float pos = ((float)n + 0.5f) * (1.f / 256.f) - 0.5f;
          pos = fminf(fmaxf(pos, 0.f), 511.f);
          float fi = floorf(pos);
          int i0 = (int)fi;
          int i1 = min(i0 + 1, 511);
          float fr = pos - fi;
          float u = rp[i0] * (1.f - fr) + rp[i1] * fr;
          e = u * npz[n];
        }
        P.h[k] = (_Float16)(e * 1024.f);
      }
      int g = x >> 3;
      int sig = g ^ ((g >> 3) & 7);
      er32[sig * 4 + ((x & 7) >> 1)] = P.u;
    }
  }
  __syncthreads();

  const int w = tid >> 6;
  const int l = tid & 63;
  const int row = l & 31;   // A-row m == B-col n lane index
  const int h = l >> 5;     // k-half

  // A granule bases (sg=0): T0 = 2w, T1 = 2w+1
  const int gaA = 2048 - 256 * w + 4 * row + h;
  const int gaB = gaA - 128;
  // B granule base (sg=0, j=0)
  const int qcb = (row & 7) * FC_STRIDE + (row >> 3) + h;

  f32x16 p00, p01, p10, p11;   // acc(T0,ph0) (T0,ph1) (T1,ph0) (T1,ph1)
#pragma unroll
  for (int i = 0; i < 16; ++i) { p00[i] = 0.f; p01[i] = 0.f; p10[i] = 0.f; p11[i] = 0.f; }

#define LOADA(DST, GB, SG_)                                                   \
  { int g = (GB) + 2 * (SG_); int ab = (g ^ ((g >> 3) & 7)) << 4;             \
    DST.u = *(const uint4*)(erb + ab); }
#define LOADBF(DST, SG_, J_)                                                  \
  { int gb = qcb + 2 * (SG_) + 128 * (J_);                                    \
    DST.u = *(const uint4*)(fcb + (gb << 4)); }

  // ---- prologue: sg = 0,1, phase 0 only ----
  for (int sg = 0; sg < 2; ++sg) {
    Frag B0, A0, A1;
    LOADBF(B0, sg, 0)
    LOADA(A0, gaA, sg) LOADA(A1, gaB, sg)
    p00 = __builtin_amdgcn_mfma_f32_32x32x16_f16(A0.v, B0.v, p00, 0, 0, 0);
    p10 = __builtin_amdgcn_mfma_f32_32x32x16_f16(A1.v, B0.v, p10, 0, 0, 0);
  }
  // ---- main: sg = 2..65, both phases (A shared across phases) ----
  for (int sg = 2; sg < 66; ++sg) {
    Frag B0, B1, A0, A1;
    LOADBF(B0, sg, 0) LOADBF(B1, sg, 1)
    LOADA(A0, gaA, sg) LOADA(A1, gaB, sg)
    p00 = __builtin_amdgcn_mfma_f32_32x32x16_f16(A0.v, B0.v, p00, 0, 0, 0);
    p01 = __builtin_amdgcn_mfma_f32_32x32x16_f16(A0.v, B1.v, p01, 0, 0, 0);
    p10 = __builtin_amdgcn_mfma_f32_32x32x16_f16(A1.v, B0.v, p10, 0, 0, 0);
    p11 = __builtin_amdgcn_mfma_f32_32x32x16_f16(A1.v, B1.v, p11, 0, 0, 0);
  }

  // ---- global-top orphan strip: extra phase-0 for T=16 (seg 7 only) ----
  if (seg == 7 && w == 7) {
    f32x16 ax;
#pragma unroll
    for (int i = 0; i < 16; ++i) ax[i] = 0.f;
    const int ge = 4 * row + h;        // 2048 - 128*16 + 4row + h
    for (int sg = 0; sg < 66; ++sg) {
      Frag Bx, Ax;
      LOADBF(Bx, sg, 0)
      LOADA(Ax, ge, sg)
      ax = __builtin_amdgcn_mfma_f32_32x32x16_f16(Ax.v, Bx.v, ax, 0, 0, 0);
    }
#pragma unroll
    for (int i = 0; i < 16; ++i) p11[i] += ax[i];
  }
#undef LOADA
#undef LOADBF

  // ---- epilogue ----
  float* cbase = outp + (size_t)chan * NS;
  const float scale = 1.f / 1024.f;

  // full outputs at NB + 1024*(2w+1): acc(2w+1,0) + acc(2w,1)
  {
    float* po = cbase + NB + 1024 * (2 * w + 1);
#pragma unroll
    for (int rg = 0; rg < 16; ++rg) {
      int crow = (rg & 3) + 8 * (rg >> 2) + 4 * h;
      po[row - 32 * crow] = (p10[rg] + p01[rg]) * scale;
    }
  }

  // exchange p11 = acc(2w+1,1) -> wave w+1 (partner of its p00)
  __syncthreads();                       // everyone done reading er
  float* scr = (float*)smem;             // 8 waves x 16 regs x 64 lanes
#pragma unroll
  for (int rg = 0; rg < 16; ++rg) scr[w * 1024 + rg * 64 + l] = p11[rg];
  __syncthreads();

  if (w >= 1) {
    float* po = cbase + NB + 1024 * (2 * w);
#pragma unroll
    for (int rg = 0; rg < 16; ++rg) {
      int crow = (rg & 3) + 8 * (rg >> 2) + 4 * h;
      po[row - 32 * crow] = (p00[rg] + scr[(w - 1) * 1024 + rg * 64 + l]) * scale;
    }
  } else {
    // w == 0: partial strip [NB-992, NB+32) -> atomicAdd (pre-zeroed)
#pragma unroll
    for (int rg = 0; rg < 16; ++rg) {
      int crow = (rg & 3) + 8 * (rg >> 2) + 4 * h;
      int y = NB + row - 32 * crow;
      if (y >= 0) atomicAdd(cbase + y, p00[rg] * scale);
    }
  }
  if (w == 7) {
    // partial strip [NB+SPAN-992, NB+SPAN+32) -> atomicAdd (pre-zeroed)
#pragma unroll
    for (int rg = 0; rg < 16; ++rg) {
      int crow = (rg & 3) + 8 * (rg >> 2) + 4 * h;
      int y = NB + SPAN + row - 32 * crow;
      if (y < NS) atomicAdd(cbase + y, p11[rg] * scale);
    }
  }
}

// ---------------------------------------------------------------------------
extern "C" void kernel_launch(void* const* d_in, const int* in_sizes, int n_in,
                              void* d_out, int out_size, void* d_ws, size_t ws_size,
                              hipStream_t stream) {
  const float* forces     = (const float*)d_in[0];
  const float* dmod       = (const float*)d_in[1];
  const float* noise      = (const float*)d_in[2];
  const float* dparam     = (const float*)d_in[3];
  const float* routing    = (const float*)d_in[4];
  const float* W1         = (const float*)d_in[5];
  const float* b1         = (const float*)d_in[6];
  const float* W2         = (const float*)d_in[7];
  const float* b2         = (const float*)d_in[8];
  const float* filters    = (const float*)d_in[9];
  const float* to_control = (const float*)d_in[10];

  float* out = (float*)d_out;
  float* to_ctrl = out;                                  // (B,CPD,NF)
  float* reso = out + BATCH * CPD * NF;                  // (B,RES,NS)

  float* damped_t = (float*)d_ws;                        // (B,NF,CPD)
  float* routed = damped_t + BATCH * NF * CPD;           // (B,RES,NF)

  k_scan<<<BATCH, 256, 0, stream>>>(forces, dmod, dparam, damped_t);
  k_hyper<<<BATCH * NF / 4, 256, 0, stream>>>(damped_t, routing, W1, b1, W2, b2,
                                              to_control, routed, to_ctrl);
  k_zero<<<BATCH * RES, 256, 0, stream>>>(reso);
  k_conv<<<BATCH * RES * (NS / SPAN), 512, 0, stream>>>(routed, noise, filters, reso);
}